// Round 1
// baseline (197.256 us; speedup 1.0000x reference)
//
#include <hip/hip_runtime.h>

#define BATCH 32
#define EMB_DIM 256
#define HW 4096
#define N_EMB 1024
#define N_ROWS (BATCH * HW)            // 131072
#define TOT_ELEMS (N_ROWS * EMB_DIM)   // 33554432

typedef __attribute__((ext_vector_type(8))) short bf16x8;
typedef __attribute__((ext_vector_type(4))) float f32x4;

// ws layout (bytes)
#define WS_EMB_OFF 0              // 512 KB swizzled bf16 emb
#define WS_E2_OFF  524288         // 1024 f32 (sum of squares per emb)
#define WS_PX2_OFF 528384         // 2048 f32 copy-kernel partials
#define WS_PSC_OFF 536576         // 512 f32 vq-kernel partials

#define COPY_BLOCKS 2048
#define MAIN_BLOCKS 512           // 256 rows per block

__device__ __forceinline__ unsigned short f2bf(float f) {
    unsigned int u = __builtin_bit_cast(unsigned int, f);
    u += 0x7FFFu + ((u >> 16) & 1u);   // round-to-nearest-even
    return (unsigned short)(u >> 16);
}

// ---------------------------------------------------------------------------
// Kernel 0: emb fp32 -> bf16, pre-swizzled chunk layout + e2 = ||e||^2.
// Layout: chunk = e>>6 (64 e per 32KB chunk), row el = e&63 (512B rows),
//         byte cb within row stored at cb ^ ((el&31)<<4).
// ---------------------------------------------------------------------------
__global__ __launch_bounds__(64) void prep_emb(const float* __restrict__ emb,
                                               unsigned long long* __restrict__ embsw,
                                               float* __restrict__ e2) {
    const int e = blockIdx.x, ln = threadIdx.x;
    const float4 v = reinterpret_cast<const float4*>(emb)[e * 64 + ln];
    float s = v.x * v.x + v.y * v.y + v.z * v.z + v.w * v.w;

    unsigned long long pk = (unsigned long long)f2bf(v.x)
                          | ((unsigned long long)f2bf(v.y) << 16)
                          | ((unsigned long long)f2bf(v.z) << 32)
                          | ((unsigned long long)f2bf(v.w) << 48);
    const int el = e & 63, ch = e >> 6;
    const int cb = ln * 8;
    const int off = (ch << 15) + (el << 9) + (cb ^ ((el & 31) << 4));
    *reinterpret_cast<unsigned long long*>(reinterpret_cast<char*>(embsw) + off) = pk;

#pragma unroll
    for (int o = 32; o; o >>= 1) s += __shfl_down(s, o);
    if (ln == 0) e2[e] = s;
}

// ---------------------------------------------------------------------------
// Kernel 1: out[0..N) = x, plus block partials of sum(x^2).
// ---------------------------------------------------------------------------
__global__ __launch_bounds__(256) void copy_x2(const float4* __restrict__ x4,
                                               float4* __restrict__ o4,
                                               float* __restrict__ px2) {
    const int idx = blockIdx.x * 256 + threadIdx.x;
    float s = 0.f;
#pragma unroll
    for (int i = 0; i < TOT_ELEMS / 4 / (COPY_BLOCKS * 256); ++i) {
        const int k = idx + i * (COPY_BLOCKS * 256);
        const float4 v = x4[k];
        o4[k] = v;
        s += v.x * v.x + v.y * v.y + v.z * v.z + v.w * v.w;
    }
#pragma unroll
    for (int o = 32; o; o >>= 1) s += __shfl_down(s, o);
    __shared__ float wsum[4];
    const int wv = threadIdx.x >> 6, ln = threadIdx.x & 63;
    if (ln == 0) wsum[wv] = s;
    __syncthreads();
    if (threadIdx.x == 0) px2[blockIdx.x] = (wsum[0] + wsum[1]) + (wsum[2] + wsum[3]);
}

// ---------------------------------------------------------------------------
// Kernel 2: fused GEMM + min-reduction.
// Block: 256 threads (4 waves), 256 rows. Wave owns 64 rows as 4 B-frag sets.
// A = emb tile (16e x 32k), B = x rows (32k x 16m):
//   A frag: lane holds A[l&15][8*(l>>4)+j]  (k-contiguous bf16x8)
//   B frag: lane holds B[8*(l>>4)+j][l&15]
//   D:      lane,reg -> D[e = 4*(l>>4)+reg][m = l&15]
// ---------------------------------------------------------------------------
__global__ __launch_bounds__(256, 2) void vq_main(const float* __restrict__ x,
                                                  const uint4* __restrict__ embsw,
                                                  const float* __restrict__ e2,
                                                  float* __restrict__ psc) {
    __shared__ uint4 smem4[4096];          // 2 x 32KB emb chunk buffers
    const int tid = threadIdx.x;
    const int wv = tid >> 6, ln = tid & 63;
    const int u = ln & 15, g = ln >> 4;    // m-lane, k-group

    const int row_base = blockIdx.x << 8;
    const int b = row_base >> 12, n_base = row_base & 4095;
    const float* xb = x + b * (EMB_DIM * HW) + n_base + wv * 64 + u;

    // ---- load x fragments (fp32 -> bf16 in regs), read x exactly once ----
    bf16x8 bx[4][8];
#pragma unroll
    for (int s_ = 0; s_ < 4; ++s_) {
#pragma unroll
        for (int kf = 0; kf < 8; ++kf) {
            const float* p = xb + s_ * 16 + (kf * 32 + g * 8) * HW;
            bf16x8 v;
#pragma unroll
            for (int j = 0; j < 8; ++j) v[j] = (short)f2bf(p[j * HW]);
            bx[s_][kf] = v;
        }
    }

    const char* smemb = reinterpret_cast<const char*>(smem4);
    float best[4] = {3.0e38f, 3.0e38f, 3.0e38f, 3.0e38f};
    uint4 rg[8];

    // prologue: stage chunk 0
#pragma unroll
    for (int i = 0; i < 8; ++i) rg[i] = embsw[tid + i * 256];
#pragma unroll
    for (int i = 0; i < 8; ++i) smem4[tid + i * 256] = rg[i];
    __syncthreads();

    for (int c = 0; c < 16; ++c) {
        if (c < 15) {                       // issue next chunk's global loads early
            const uint4* src = embsw + (c + 1) * 2048 + tid;
#pragma unroll
            for (int i = 0; i < 8; ++i) rg[i] = src[i * 256];
        }
        const char* bufb = smemb + (c & 1) * 32768;
#pragma unroll
        for (int t = 0; t < 4; ++t) {
            const int el = t * 16 + u;
            const f32x4 ev = *reinterpret_cast<const f32x4*>(e2 + c * 64 + t * 16 + g * 4);
            f32x4 a0 = {0.f, 0.f, 0.f, 0.f}, a1 = a0, a2 = a0, a3 = a0;
#pragma unroll
            for (int kf = 0; kf < 8; ++kf) {
                const int off = el * 512 + ((kf * 64 + g * 16) ^ ((el & 31) << 4));
                const bf16x8 a = *reinterpret_cast<const bf16x8*>(bufb + off);
                a0 = __builtin_amdgcn_mfma_f32_16x16x32_bf16(a, bx[0][kf], a0, 0, 0, 0);
                a1 = __builtin_amdgcn_mfma_f32_16x16x32_bf16(a, bx[1][kf], a1, 0, 0, 0);
                a2 = __builtin_amdgcn_mfma_f32_16x16x32_bf16(a, bx[2][kf], a2, 0, 0, 0);
                a3 = __builtin_amdgcn_mfma_f32_16x16x32_bf16(a, bx[3][kf], a3, 0, 0, 0);
            }
#pragma unroll
            for (int r = 0; r < 4; ++r) {
                best[0] = fminf(best[0], fmaf(-2.f, a0[r], ev[r]));
                best[1] = fminf(best[1], fmaf(-2.f, a1[r], ev[r]));
                best[2] = fminf(best[2], fmaf(-2.f, a2[r], ev[r]));
                best[3] = fminf(best[3], fmaf(-2.f, a3[r], ev[r]));
            }
        }
        __syncthreads();                    // all waves done reading buf[c&1]
        if (c < 15) {
            uint4* dst = smem4 + ((c + 1) & 1) * 2048;
#pragma unroll
            for (int i = 0; i < 8; ++i) dst[tid + i * 256] = rg[i];
        }
        __syncthreads();                    // staged chunk visible
    }

    // combine the 4 k-groups (each saw a disjoint quarter of the e's)
#pragma unroll
    for (int s_ = 0; s_ < 4; ++s_) {
        best[s_] = fminf(best[s_], __shfl_xor(best[s_], 16));
        best[s_] = fminf(best[s_], __shfl_xor(best[s_], 32));
    }
    float contrib = (g == 0) ? ((best[0] + best[1]) + (best[2] + best[3])) : 0.f;
#pragma unroll
    for (int o = 32; o; o >>= 1) contrib += __shfl_down(contrib, o);

    __shared__ float wsum[4];
    if (ln == 0) wsum[wv] = contrib;
    __syncthreads();
    if (tid == 0) psc[blockIdx.x] = (wsum[0] + wsum[1]) + (wsum[2] + wsum[3]);
}

// ---------------------------------------------------------------------------
// Kernel 3: deterministic tree-reduce of partials -> loss scalar.
// ---------------------------------------------------------------------------
__global__ __launch_bounds__(256) void finalize(const float* __restrict__ px2,
                                                const float* __restrict__ psc,
                                                float* __restrict__ out_loss) {
    __shared__ float red[256];
    const int t = threadIdx.x;
    float s = 0.f;
#pragma unroll
    for (int i = 0; i < COPY_BLOCKS / 256; ++i) s += px2[t + i * 256];
#pragma unroll
    for (int i = 0; i < MAIN_BLOCKS / 256; ++i) s += psc[t + i * 256];
    red[t] = s;
    __syncthreads();
    for (int h = 128; h; h >>= 1) {
        if (t < h) red[t] += red[t + h];
        __syncthreads();
    }
    if (t == 0) *out_loss = 1.25f * red[0] / (float)TOT_ELEMS;
}

extern "C" void kernel_launch(void* const* d_in, const int* in_sizes, int n_in,
                              void* d_out, int out_size, void* d_ws, size_t ws_size,
                              hipStream_t stream) {
    const float* x = (const float*)d_in[0];
    const float* emb = (const float*)d_in[1];
    float* out = (float*)d_out;
    char* ws = (char*)d_ws;

    unsigned long long* embsw = (unsigned long long*)(ws + WS_EMB_OFF);
    float* e2  = (float*)(ws + WS_E2_OFF);
    float* px2 = (float*)(ws + WS_PX2_OFF);
    float* psc = (float*)(ws + WS_PSC_OFF);

    prep_emb<<<N_EMB, 64, 0, stream>>>(emb, embsw, e2);
    copy_x2<<<COPY_BLOCKS, 256, 0, stream>>>((const float4*)x, (float4*)out, px2);
    vq_main<<<MAIN_BLOCKS, 256, 0, stream>>>(x, (const uint4*)(ws + WS_EMB_OFF), e2, psc);
    finalize<<<1, 256, 0, stream>>>(px2, psc, out + TOT_ELEMS);
}